// Round 1
// baseline (337.193 us; speedup 1.0000x reference)
//
#include <hip/hip_runtime.h>

#define NB 64
#define CH 128
#define NNODE 2048
#define NH 4
#define DKK 32
#define INVS 0.17677669529663687f

typedef __bf16 bf16x8 __attribute__((ext_vector_type(8)));
typedef float f32x4 __attribute__((ext_vector_type(4)));
typedef unsigned short ushort_t;

union U16x8 { uint4 u; bf16x8 b; unsigned short s[8]; };

__device__ inline bf16x8 as_bf16x8(uint4 u){ U16x8 x; x.u = u; return x.b; }
__device__ inline unsigned short f2b(float f){ __bf16 h = (__bf16)f; return __builtin_bit_cast(unsigned short, h); }
__device__ inline float b2f(unsigned short u){ __bf16 h = __builtin_bit_cast(__bf16, u); return (float)h; }

// ---------------------------------------------------------------------------
// k0_prep: convert conv weights to bf16, softmax(memory/scale) -> keys, zero kv
// grid 256 x 256  (gid < 65536)
// ---------------------------------------------------------------------------
__global__ __launch_bounds__(256) void k0_prep(const float* __restrict__ qw,
    const float* __restrict__ vw, const float* __restrict__ cw,
    const float* __restrict__ memory,
    ushort_t* __restrict__ wqb, ushort_t* __restrict__ wvb, ushort_t* __restrict__ wcb,
    float* __restrict__ keys, float* __restrict__ kvws)
{
  int gid = blockIdx.x * 256 + threadIdx.x;
  if (gid < 16384) { wqb[gid] = f2b(qw[gid]); wvb[gid] = f2b(vw[gid]); wcb[gid] = f2b(cw[gid]); }
  { f32x4 z = {0.f,0.f,0.f,0.f}; *(f32x4*)(kvws + (size_t)gid * 4) = z; }
  if (gid < 8192) {  // one row (h,n) of 32: softmax(memory * invscale)
    const float* src = memory + (size_t)gid * 32;
    float v[32]; float m = -1e30f;
    #pragma unroll
    for (int i = 0; i < 32; ++i) { v[i] = src[i] * INVS; m = fmaxf(m, v[i]); }
    float s = 0.f;
    #pragma unroll
    for (int i = 0; i < 32; ++i) { v[i] = __expf(v[i] - m); s += v[i]; }
    float inv = 1.f / s;
    float* dst = keys + (size_t)gid * 32;
    #pragma unroll
    for (int i = 0; i < 32; ++i) dst[i] = v[i] * inv;
  }
}

// ---------------------------------------------------------------------------
// k0_bias: bias_dyn[n][k] = softmax_m(relu(nv1[n]·nv2[:,m])) @ bias_pool
// grid 2048 (one block per node row n) x 256
// ---------------------------------------------------------------------------
__global__ __launch_bounds__(256) void k0_bias(const float* __restrict__ nv1,
    const float* __restrict__ nv2, const float* __restrict__ bias_pool,
    float* __restrict__ bias_dyn)
{
  int n = blockIdx.x; int tid = threadIdx.x;
  __shared__ float red[4][33];
  float a1[10];
  #pragma unroll
  for (int d = 0; d < 10; ++d) a1[d] = nv1[n * 10 + d];
  float acc[32];
  #pragma unroll
  for (int k = 0; k < 32; ++k) acc[k] = 0.f;
  float denom = 0.f;
  for (int m = tid; m < 2048; m += 256) {
    float s = 0.f;
    #pragma unroll
    for (int d = 0; d < 10; ++d) s += a1[d] * nv2[d * 2048 + m];
    s = fmaxf(s, 0.f);            // relu; values in [0,~20] -> exp safe in fp32
    float e = __expf(s);
    denom += e;
    const float* bp = bias_pool + m * 32;
    #pragma unroll
    for (int k = 0; k < 32; ++k) acc[k] += e * bp[k];
  }
  #pragma unroll
  for (int d = 1; d < 64; d <<= 1) {
    denom += __shfl_xor(denom, d);
    #pragma unroll
    for (int k = 0; k < 32; ++k) acc[k] += __shfl_xor(acc[k], d);
  }
  int wv = tid >> 6, lane = tid & 63;
  if (lane == 0) {
    #pragma unroll
    for (int k = 0; k < 32; ++k) red[wv][k] = acc[k];
    red[wv][32] = denom;
  }
  __syncthreads();
  if (tid < 32) {
    float s = red[0][tid] + red[1][tid] + red[2][tid] + red[3][tid];
    float dn = red[0][32] + red[1][32] + red[2][32] + red[3][32];
    bias_dyn[n * 32 + tid] = s / dn;
  }
}

// ---------------------------------------------------------------------------
// k1_qv: Q = softmax_head(relu(Wq x)/scale), V = relu(Wv x); stores QsT,VT as
// bf16 [b][n][128]. Block: 32 nodes of one b; wave w owns head w (32 chans).
// grid 64*64 = 4096 x 256
// ---------------------------------------------------------------------------
__global__ __launch_bounds__(256) void k1_qv(const float* __restrict__ x,
    const ushort_t* __restrict__ wqb, const ushort_t* __restrict__ wvb,
    const float* __restrict__ qbias, const float* __restrict__ vbias,
    ushort_t* __restrict__ QsT, ushort_t* __restrict__ VT)
{
  int bid = blockIdx.x; int b = bid >> 6; int n0 = (bid & 63) * 32;
  int tid = threadIdx.x; int wv = tid >> 6; int lane = tid & 63;
  int quad = lane >> 4; int l16 = lane & 15;
  __shared__ __align__(16) ushort_t XT[32][136];   // 8.7 KB, reused as out buffer

  // cache W B-frags in registers: B[k=c][col=o] = W[o][c], 8 contiguous c / lane
  uint4 wq[2][4], wvv[2][4];
  #pragma unroll
  for (int ct = 0; ct < 2; ++ct)
    #pragma unroll
    for (int k0 = 0; k0 < 4; ++k0) {
      int off = (32 * wv + 16 * ct + l16) * 128 + 32 * k0 + 8 * quad;
      wq[ct][k0]  = *(const uint4*)(wqb + off);
      wvv[ct][k0] = *(const uint4*)(wvb + off);
    }
  float qb[2], vb[2];
  #pragma unroll
  for (int ct = 0; ct < 2; ++ct) {
    qb[ct] = qbias[32 * wv + 16 * ct + l16];
    vb[ct] = vbias[32 * wv + 16 * ct + l16];
  }

  // stage X tile [128 c][32 n] fp32 -> XT[n][c] bf16 (transpose)
  #pragma unroll
  for (int p = 0; p < 4; ++p) {
    int c = 32 * p + (tid >> 3); int i = tid & 7;
    float4 v4 = *(const float4*)(x + (size_t)(b * 128 + c) * 2048 + n0 + 4 * i);
    XT[4*i+0][c] = f2b(v4.x); XT[4*i+1][c] = f2b(v4.y);
    XT[4*i+2][c] = f2b(v4.z); XT[4*i+3][c] = f2b(v4.w);
  }
  __syncthreads();

  f32x4 zero4 = {0.f,0.f,0.f,0.f};
  f32x4 accq[2][2], accv[2][2];
  #pragma unroll
  for (int i = 0; i < 2; ++i)
    #pragma unroll
    for (int j = 0; j < 2; ++j) { accq[i][j] = zero4; accv[i][j] = zero4; }

  #pragma unroll
  for (int k0 = 0; k0 < 4; ++k0) {
    bf16x8 a0 = *(const bf16x8*)&XT[l16][32 * k0 + 8 * quad];
    bf16x8 a1 = *(const bf16x8*)&XT[16 + l16][32 * k0 + 8 * quad];
    #pragma unroll
    for (int ct = 0; ct < 2; ++ct) {
      accq[0][ct] = __builtin_amdgcn_mfma_f32_16x16x32_bf16(a0, as_bf16x8(wq[ct][k0]),  accq[0][ct], 0, 0, 0);
      accq[1][ct] = __builtin_amdgcn_mfma_f32_16x16x32_bf16(a1, as_bf16x8(wq[ct][k0]),  accq[1][ct], 0, 0, 0);
      accv[0][ct] = __builtin_amdgcn_mfma_f32_16x16x32_bf16(a0, as_bf16x8(wvv[ct][k0]), accv[0][ct], 0, 0, 0);
      accv[1][ct] = __builtin_amdgcn_mfma_f32_16x16x32_bf16(a1, as_bf16x8(wvv[ct][k0]), accv[1][ct], 0, 0, 0);
    }
  }

  // epilogue: relu(+bias); query softmax over the head's 32 channels per n-row
  #pragma unroll
  for (int nt = 0; nt < 2; ++nt) {
    float sq[2][4];
    #pragma unroll
    for (int ct = 0; ct < 2; ++ct)
      #pragma unroll
      for (int r = 0; r < 4; ++r)
        sq[ct][r] = fmaxf(accq[nt][ct][r] + qb[ct], 0.f) * INVS;
    #pragma unroll
    for (int r = 0; r < 4; ++r) {
      float m = fmaxf(sq[0][r], sq[1][r]);
      m = fmaxf(m, __shfl_xor(m, 1)); m = fmaxf(m, __shfl_xor(m, 2));
      m = fmaxf(m, __shfl_xor(m, 4)); m = fmaxf(m, __shfl_xor(m, 8));
      float e0 = __expf(sq[0][r] - m), e1 = __expf(sq[1][r] - m);
      float s = e0 + e1;
      s += __shfl_xor(s, 1); s += __shfl_xor(s, 2);
      s += __shfl_xor(s, 4); s += __shfl_xor(s, 8);
      float inv = 1.f / s;
      accq[nt][0][r] = e0 * inv; accq[nt][1][r] = e1 * inv;
    }
    #pragma unroll
    for (int ct = 0; ct < 2; ++ct)
      #pragma unroll
      for (int r = 0; r < 4; ++r)
        accv[nt][ct][r] = fmaxf(accv[nt][ct][r] + vb[ct], 0.f);
  }

  // Q -> LDS -> coalesced global (bf16 [b][n][128])
  __syncthreads();
  #pragma unroll
  for (int nt = 0; nt < 2; ++nt)
    #pragma unroll
    for (int ct = 0; ct < 2; ++ct)
      #pragma unroll
      for (int r = 0; r < 4; ++r)
        XT[16*nt + 4*quad + r][32*wv + 16*ct + l16] = f2b(accq[nt][ct][r]);
  __syncthreads();
  #pragma unroll
  for (int j = 0; j < 2; ++j) {
    int id = tid + 256 * j; int n = id >> 4; int u = id & 15;
    *(uint4*)(QsT + (size_t)(b * 2048 + n0 + n) * 128 + 8 * u) = *(uint4*)&XT[n][8 * u];
  }
  __syncthreads();
  #pragma unroll
  for (int nt = 0; nt < 2; ++nt)
    #pragma unroll
    for (int ct = 0; ct < 2; ++ct)
      #pragma unroll
      for (int r = 0; r < 4; ++r)
        XT[16*nt + 4*quad + r][32*wv + 16*ct + l16] = f2b(accv[nt][ct][r]);
  __syncthreads();
  #pragma unroll
  for (int j = 0; j < 2; ++j) {
    int id = tid + 256 * j; int n = id >> 4; int u = id & 15;
    *(uint4*)(VT + (size_t)(b * 2048 + n0 + n) * 128 + 8 * u) = *(uint4*)&XT[n][8 * u];
  }
}

// ---------------------------------------------------------------------------
// k2_kv: kv[b,h,x,y] = sum_n keys[h,n,x] * V[b,h,n,y]; stored as [b][h][y][x]
// grid 64*16 = 1024 x 256; block handles 128 nodes, atomicAdd partials
// ---------------------------------------------------------------------------
__global__ __launch_bounds__(256) void k2_kv(const float* __restrict__ keys,
    const ushort_t* __restrict__ VT, float* __restrict__ kvws)
{
  int bid = blockIdx.x; int b = bid >> 4; int n0 = (bid & 15) * 128;
  int tid = threadIdx.x;
  int h = tid >> 6; int t64 = tid & 63; int a = t64 >> 3; int bg = t64 & 7;
  __shared__ __align__(16) float K_lds[32][128];
  __shared__ __align__(16) float V_lds[32][128];
  f32x4 zero4 = {0.f,0.f,0.f,0.f};
  f32x4 acc[4];
  #pragma unroll
  for (int i = 0; i < 4; ++i) acc[i] = zero4;
  for (int sub = 0; sub < 4; ++sub) {
    int nb = n0 + 32 * sub;
    #pragma unroll
    for (int p = 0; p < 4; ++p) {
      int id = tid + 256 * p; int nl = id >> 5; int q4 = id & 31; int c = 4 * q4;
      int hh = c >> 5; int xx = c & 31;
      *(float4*)&K_lds[nl][c] = *(const float4*)(keys + (size_t)(hh * 2048 + nb + nl) * 32 + xx);
    }
    #pragma unroll
    for (int p = 0; p < 2; ++p) {
      int id = tid + 256 * p; int nl = id >> 4; int g = id & 15;
      U16x8 raw; raw.u = *(const uint4*)(VT + (size_t)(b * 2048 + nb + nl) * 128 + 8 * g);
      #pragma unroll
      for (int e = 0; e < 8; ++e) V_lds[nl][8 * g + e] = b2f(raw.s[e]);
    }
    __syncthreads();
    #pragma unroll 4
    for (int nl = 0; nl < 32; ++nl) {
      f32x4 kx = *(const f32x4*)&K_lds[nl][h * 32 + 4 * a];
      f32x4 vy = *(const f32x4*)&V_lds[nl][h * 32 + 4 * bg];
      acc[0] += kx[0] * vy; acc[1] += kx[1] * vy;
      acc[2] += kx[2] * vy; acc[3] += kx[3] * vy;
    }
    __syncthreads();
  }
  #pragma unroll
  for (int i = 0; i < 4; ++i)
    #pragma unroll
    for (int j = 0; j < 4; ++j)
      atomicAdd(kvws + (size_t)((b * 4 + h) * 32 + 4 * bg + j) * 32 + 4 * a + i, acc[i][j]);
}

// ---------------------------------------------------------------------------
// k3_out: attn_qkv (block-diag GEMM, K=32/head) + Ws*V + bias_dyn -> MID(LDS),
// then final conv GEMM + relu + affine residual. Block: 64 nodes of one b.
// grid 64*32 = 2048 x 256; wave w owns head w / c_out group w
// ---------------------------------------------------------------------------
__global__ __launch_bounds__(256) void k3_out(const ushort_t* __restrict__ QsT,
    const ushort_t* __restrict__ VT, const float* __restrict__ kvws,
    const float* __restrict__ bias_dyn, const ushort_t* __restrict__ wcb,
    const float* __restrict__ cbias, const float* __restrict__ wpool,
    const float* __restrict__ aff_w, const float* __restrict__ aff_b,
    float* __restrict__ out)
{
  int bid = blockIdx.x; int b = bid >> 5; int n0 = (bid & 31) * 64;
  int tid = threadIdx.x; int wv = tid >> 6; int lane = tid & 63;
  int quad = lane >> 4; int l16 = lane & 15;
  __shared__ __align__(16) ushort_t kvT[4][32][40];   // [h][y][x] bf16, padded
  __shared__ __align__(16) ushort_t MID[64][136];

  float Ws = 0.f;
  #pragma unroll
  for (int i = 0; i < 9; ++i) Ws += wpool[i];

  uint4 wc[2][4];
  #pragma unroll
  for (int mt = 0; mt < 2; ++mt)
    #pragma unroll
    for (int k0 = 0; k0 < 4; ++k0)
      wc[mt][k0] = *(const uint4*)(wcb + (32 * wv + 16 * mt + l16) * 128 + 32 * k0 + 8 * quad);

  #pragma unroll
  for (int p = 0; p < 16; ++p) {
    int id = tid + 256 * p;
    kvT[id >> 10][(id >> 5) & 31][id & 31] = f2b(kvws[(size_t)b * 4096 + id]);
  }
  __syncthreads();

  f32x4 zero4 = {0.f,0.f,0.f,0.f};
  f32x4 acc1[4][2];
  #pragma unroll
  for (int nt = 0; nt < 4; ++nt) { acc1[nt][0] = zero4; acc1[nt][1] = zero4; }
  #pragma unroll
  for (int nt = 0; nt < 4; ++nt) {
    bf16x8 aq = *(const bf16x8*)(QsT + (size_t)(b * 2048 + n0 + 16 * nt + l16) * 128 + 32 * wv + 8 * quad);
    #pragma unroll
    for (int ct = 0; ct < 2; ++ct)
      acc1[nt][ct] = __builtin_amdgcn_mfma_f32_16x16x32_bf16(
          aq, *(const bf16x8*)&kvT[wv][16 * ct + l16][8 * quad], acc1[nt][ct], 0, 0, 0);
  }

  // epilogue 1: MID = attn_qkv + Ws*V + bias_dyn (bf16 in LDS)
  #pragma unroll
  for (int nt = 0; nt < 4; ++nt)
    #pragma unroll
    for (int ct = 0; ct < 2; ++ct)
      #pragma unroll
      for (int r = 0; r < 4; ++r) {
        int nl = 16 * nt + 4 * quad + r; int nn = n0 + nl;
        int cc = 32 * wv + 16 * ct + l16;
        float v = b2f(VT[(size_t)(b * 2048 + nn) * 128 + cc]);
        float bd = bias_dyn[nn * 32 + 16 * ct + l16];
        MID[nl][cc] = f2b(acc1[nt][ct][r] + Ws * v + bd);
      }
  __syncthreads();

  f32x4 acc2[2][4];
  #pragma unroll
  for (int mt = 0; mt < 2; ++mt)
    #pragma unroll
    for (int nt = 0; nt < 4; ++nt) acc2[mt][nt] = zero4;
  #pragma unroll
  for (int k0 = 0; k0 < 4; ++k0) {
    bf16x8 bb[4];
    #pragma unroll
    for (int nt = 0; nt < 4; ++nt)
      bb[nt] = *(const bf16x8*)&MID[16 * nt + l16][32 * k0 + 8 * quad];
    #pragma unroll
    for (int mt = 0; mt < 2; ++mt)
      #pragma unroll
      for (int nt = 0; nt < 4; ++nt)
        acc2[mt][nt] = __builtin_amdgcn_mfma_f32_16x16x32_bf16(
            as_bf16x8(wc[mt][k0]), bb[nt], acc2[mt][nt], 0, 0, 0);
  }

  // epilogue 2: relu(+cb), affine residual, store fp32
  #pragma unroll
  for (int mt = 0; mt < 2; ++mt)
    #pragma unroll
    for (int nt = 0; nt < 4; ++nt)
      #pragma unroll
      for (int r = 0; r < 4; ++r) {
        int c_out = 32 * wv + 16 * mt + 4 * quad + r;
        int nn2 = n0 + 16 * nt + l16;
        float yv = fmaxf(acc2[mt][nt][r] + cbias[c_out], 0.f);
        size_t ai = (size_t)c_out * 2048 + nn2;
        float awv = aff_w[ai], abv = aff_b[ai];
        out[(size_t)(b * 128 + c_out) * 2048 + nn2] = yv * awv + abv + yv;
      }
}

// ---------------------------------------------------------------------------
extern "C" void kernel_launch(void* const* d_in, const int* in_sizes, int n_in,
                              void* d_out, int out_size, void* d_ws, size_t ws_size,
                              hipStream_t stream)
{
  const float* x      = (const float*)d_in[0];
  const float* qw     = (const float*)d_in[1];
  const float* qb     = (const float*)d_in[2];
  const float* vw     = (const float*)d_in[3];
  const float* vb     = (const float*)d_in[4];
  const float* cw     = (const float*)d_in[5];
  const float* cb     = (const float*)d_in[6];
  const float* memory = (const float*)d_in[7];
  const float* nv1    = (const float*)d_in[8];
  const float* nv2    = (const float*)d_in[9];
  const float* wpool  = (const float*)d_in[10];
  const float* bpool  = (const float*)d_in[11];
  const float* aw     = (const float*)d_in[12];
  const float* ab     = (const float*)d_in[13];
  float* out = (float*)d_out;

  char* ws = (char*)d_ws;
  ushort_t* QsT      = (ushort_t*)(ws);                 // 33,554,432 B
  ushort_t* VT       = (ushort_t*)(ws + 33554432);      // 33,554,432 B
  float*    kvws     = (float*)   (ws + 67108864);      //  1,048,576 B
  float*    keys     = (float*)   (ws + 68157440);      //  1,048,576 B
  float*    bias_dyn = (float*)   (ws + 69206016);      //    262,144 B
  ushort_t* wqb      = (ushort_t*)(ws + 69468160);      //     32,768 B
  ushort_t* wvb      = (ushort_t*)(ws + 69500928);      //     32,768 B
  ushort_t* wcb      = (ushort_t*)(ws + 69533696);      //     32,768 B (end 69,566,464)

  k0_prep<<<256, 256, 0, stream>>>(qw, vw, cw, memory, wqb, wvb, wcb, keys, kvws);
  k0_bias<<<2048, 256, 0, stream>>>(nv1, nv2, bpool, bias_dyn);
  k1_qv<<<4096, 256, 0, stream>>>(x, wqb, wvb, qb, vb, QsT, VT);
  k2_kv<<<1024, 256, 0, stream>>>(keys, VT, kvws);
  k3_out<<<2048, 256, 0, stream>>>(QsT, VT, kvws, bias_dyn, wcb, cb, wpool, aw, ab, out);
}

// Round 2
// 273.157 us; speedup vs baseline: 1.2344x; 1.2344x over previous
//
#include <hip/hip_runtime.h>

#define NB 64
#define CH 128
#define NNODE 2048
#define NH 4
#define DKK 32
#define INVS 0.17677669529663687f

typedef __bf16 bf16x8 __attribute__((ext_vector_type(8)));
typedef float f32x4 __attribute__((ext_vector_type(4)));
typedef unsigned short ushort_t;

union U16x8 { uint4 u; bf16x8 b; unsigned short s[8]; };

__device__ inline bf16x8 as_bf16x8(uint4 u){ U16x8 x; x.u = u; return x.b; }
__device__ inline unsigned short f2b(float f){ __bf16 h = (__bf16)f; return __builtin_bit_cast(unsigned short, h); }
__device__ inline float b2f(unsigned short u){ __bf16 h = __builtin_bit_cast(__bf16, u); return (float)h; }

// ---------------------------------------------------------------------------
// k0_prep: weights->bf16, key softmax, zero kv & bias_dyn, build bpT [32][2048]
// grid 256 x 256  (gid < 65536)
// ---------------------------------------------------------------------------
__global__ __launch_bounds__(256) void k0_prep(const float* __restrict__ qw,
    const float* __restrict__ vw, const float* __restrict__ cw,
    const float* __restrict__ memory, const float* __restrict__ bias_pool,
    ushort_t* __restrict__ wqb, ushort_t* __restrict__ wvb, ushort_t* __restrict__ wcb,
    float* __restrict__ keys, float* __restrict__ kvws,
    float* __restrict__ bias_dyn, ushort_t* __restrict__ bpT)
{
  int gid = blockIdx.x * 256 + threadIdx.x;
  if (gid < 16384) { wqb[gid] = f2b(qw[gid]); wvb[gid] = f2b(vw[gid]); wcb[gid] = f2b(cw[gid]); }
  { f32x4 z = {0.f,0.f,0.f,0.f}; *(f32x4*)(kvws + (size_t)gid * 4) = z; }
  bias_dyn[gid] = 0.f;                               // 2048*32 = 65536 == grid*block
  { int k = gid >> 11, m = gid & 2047;               // bpT[k][m] = bias_pool[m][k]
    bpT[gid] = f2b(bias_pool[m * 32 + k]); }
  if (gid < 8192) {  // one row (h,n) of 32: softmax(memory * invscale)
    const float* src = memory + (size_t)gid * 32;
    float v[32]; float m = -1e30f;
    #pragma unroll
    for (int i = 0; i < 32; ++i) { v[i] = src[i] * INVS; m = fmaxf(m, v[i]); }
    float s = 0.f;
    #pragma unroll
    for (int i = 0; i < 32; ++i) { v[i] = __expf(v[i] - m); s += v[i]; }
    float inv = 1.f / s;
    float* dst = keys + (size_t)gid * 32;
    #pragma unroll
    for (int i = 0; i < 32; ++i) dst[i] = v[i] * inv;
  }
}

// ---------------------------------------------------------------------------
// kb1: normalized softmax rows of relu(nv1@nv2) -> Ebuf bf16 [2048][2048]
// grid 2048 (one block per row n) x 256; fully coalesced nv2 reads
// ---------------------------------------------------------------------------
__global__ __launch_bounds__(256) void kb1(const float* __restrict__ nv1,
    const float* __restrict__ nv2, ushort_t* __restrict__ Ebuf)
{
  int n = blockIdx.x; int tid = threadIdx.x;
  float a1[10];
  #pragma unroll
  for (int d = 0; d < 10; ++d) a1[d] = nv1[n * 10 + d];
  int m0 = tid * 8;
  float s[8];
  #pragma unroll
  for (int j = 0; j < 8; ++j) s[j] = 0.f;
  #pragma unroll
  for (int d = 0; d < 10; ++d) {
    const float* p = nv2 + d * 2048 + m0;
    float4 u = *(const float4*)p; float4 v = *(const float4*)(p + 4);
    s[0] += a1[d] * u.x; s[1] += a1[d] * u.y; s[2] += a1[d] * u.z; s[3] += a1[d] * u.w;
    s[4] += a1[d] * v.x; s[5] += a1[d] * v.y; s[6] += a1[d] * v.z; s[7] += a1[d] * v.w;
  }
  float e[8]; float sum = 0.f;
  #pragma unroll
  for (int j = 0; j < 8; ++j) { e[j] = __expf(fmaxf(s[j], 0.f)); sum += e[j]; }
  #pragma unroll
  for (int d = 1; d < 64; d <<= 1) sum += __shfl_xor(sum, d);
  __shared__ float red[4];
  if ((tid & 63) == 0) red[tid >> 6] = sum;
  __syncthreads();
  float inv = 1.f / (red[0] + red[1] + red[2] + red[3]);
  U16x8 o;
  #pragma unroll
  for (int j = 0; j < 8; ++j) o.s[j] = f2b(e[j] * inv);
  *(uint4*)(Ebuf + (size_t)n * 2048 + m0) = o.u;
}

// ---------------------------------------------------------------------------
// kb2: bias_dyn = Ebuf @ bias_pool via MFMA. M=2048,N=32,K=2048, 8-way K-split
// grid 128 x 256; atomicAdd fp32 partials (bias_dyn zeroed by k0_prep)
// ---------------------------------------------------------------------------
__global__ __launch_bounds__(256) void kb2(const ushort_t* __restrict__ Ebuf,
    const ushort_t* __restrict__ bpT, float* __restrict__ bias_dyn)
{
  int bid = blockIdx.x;
  int n0 = (bid >> 3) * 128;
  int m0 = (bid & 7) * 256;
  int tid = threadIdx.x; int wv = tid >> 6; int lane = tid & 63;
  int quad = lane >> 4; int l16 = lane & 15;
  int r0 = n0 + 32 * wv;
  f32x4 zero4 = {0.f,0.f,0.f,0.f};
  f32x4 acc[2][2];
  acc[0][0] = zero4; acc[0][1] = zero4; acc[1][0] = zero4; acc[1][1] = zero4;
  for (int ks = 0; ks < 256; ks += 32) {
    int mb = m0 + ks + 8 * quad;
    bf16x8 a0 = *(const bf16x8*)(Ebuf + (size_t)(r0 + l16) * 2048 + mb);
    bf16x8 a1 = *(const bf16x8*)(Ebuf + (size_t)(r0 + 16 + l16) * 2048 + mb);
    bf16x8 b0 = *(const bf16x8*)(bpT + (size_t)l16 * 2048 + mb);
    bf16x8 b1 = *(const bf16x8*)(bpT + (size_t)(16 + l16) * 2048 + mb);
    acc[0][0] = __builtin_amdgcn_mfma_f32_16x16x32_bf16(a0, b0, acc[0][0], 0, 0, 0);
    acc[0][1] = __builtin_amdgcn_mfma_f32_16x16x32_bf16(a0, b1, acc[0][1], 0, 0, 0);
    acc[1][0] = __builtin_amdgcn_mfma_f32_16x16x32_bf16(a1, b0, acc[1][0], 0, 0, 0);
    acc[1][1] = __builtin_amdgcn_mfma_f32_16x16x32_bf16(a1, b1, acc[1][1], 0, 0, 0);
  }
  #pragma unroll
  for (int rt = 0; rt < 2; ++rt)
    #pragma unroll
    for (int ct = 0; ct < 2; ++ct)
      #pragma unroll
      for (int r = 0; r < 4; ++r)
        atomicAdd(bias_dyn + (size_t)(r0 + 16*rt + 4*quad + r) * 32 + 16*ct + l16,
                  acc[rt][ct][r]);
}

// ---------------------------------------------------------------------------
// k1_qv: Q = softmax_head(relu(Wq x)/scale), V = relu(Wv x); stores QsT,VT as
// bf16 [b][n][128]. Block: 32 nodes of one b; wave w owns head w (32 chans).
// grid 64*64 = 4096 x 256
// ---------------------------------------------------------------------------
__global__ __launch_bounds__(256) void k1_qv(const float* __restrict__ x,
    const ushort_t* __restrict__ wqb, const ushort_t* __restrict__ wvb,
    const float* __restrict__ qbias, const float* __restrict__ vbias,
    ushort_t* __restrict__ QsT, ushort_t* __restrict__ VT)
{
  int bid = blockIdx.x; int b = bid >> 6; int n0 = (bid & 63) * 32;
  int tid = threadIdx.x; int wv = tid >> 6; int lane = tid & 63;
  int quad = lane >> 4; int l16 = lane & 15;
  __shared__ __align__(16) ushort_t XT[32][136];   // 8.7 KB, reused as out buffer

  // cache W B-frags in registers: B[k=c][col=o] = W[o][c], 8 contiguous c / lane
  uint4 wq[2][4], wvv[2][4];
  #pragma unroll
  for (int ct = 0; ct < 2; ++ct)
    #pragma unroll
    for (int k0 = 0; k0 < 4; ++k0) {
      int off = (32 * wv + 16 * ct + l16) * 128 + 32 * k0 + 8 * quad;
      wq[ct][k0]  = *(const uint4*)(wqb + off);
      wvv[ct][k0] = *(const uint4*)(wvb + off);
    }
  float qb[2], vb[2];
  #pragma unroll
  for (int ct = 0; ct < 2; ++ct) {
    qb[ct] = qbias[32 * wv + 16 * ct + l16];
    vb[ct] = vbias[32 * wv + 16 * ct + l16];
  }

  // stage X tile [128 c][32 n] fp32 -> XT[n][c] bf16 (transpose)
  #pragma unroll
  for (int p = 0; p < 4; ++p) {
    int c = 32 * p + (tid >> 3); int i = tid & 7;
    float4 v4 = *(const float4*)(x + (size_t)(b * 128 + c) * 2048 + n0 + 4 * i);
    XT[4*i+0][c] = f2b(v4.x); XT[4*i+1][c] = f2b(v4.y);
    XT[4*i+2][c] = f2b(v4.z); XT[4*i+3][c] = f2b(v4.w);
  }
  __syncthreads();

  f32x4 zero4 = {0.f,0.f,0.f,0.f};
  f32x4 accq[2][2], accv[2][2];
  #pragma unroll
  for (int i = 0; i < 2; ++i)
    #pragma unroll
    for (int j = 0; j < 2; ++j) { accq[i][j] = zero4; accv[i][j] = zero4; }

  #pragma unroll
  for (int k0 = 0; k0 < 4; ++k0) {
    bf16x8 a0 = *(const bf16x8*)&XT[l16][32 * k0 + 8 * quad];
    bf16x8 a1 = *(const bf16x8*)&XT[16 + l16][32 * k0 + 8 * quad];
    #pragma unroll
    for (int ct = 0; ct < 2; ++ct) {
      accq[0][ct] = __builtin_amdgcn_mfma_f32_16x16x32_bf16(a0, as_bf16x8(wq[ct][k0]),  accq[0][ct], 0, 0, 0);
      accq[1][ct] = __builtin_amdgcn_mfma_f32_16x16x32_bf16(a1, as_bf16x8(wq[ct][k0]),  accq[1][ct], 0, 0, 0);
      accv[0][ct] = __builtin_amdgcn_mfma_f32_16x16x32_bf16(a0, as_bf16x8(wvv[ct][k0]), accv[0][ct], 0, 0, 0);
      accv[1][ct] = __builtin_amdgcn_mfma_f32_16x16x32_bf16(a1, as_bf16x8(wvv[ct][k0]), accv[1][ct], 0, 0, 0);
    }
  }

  // epilogue: relu(+bias); query softmax over the head's 32 channels per n-row
  #pragma unroll
  for (int nt = 0; nt < 2; ++nt) {
    float sq[2][4];
    #pragma unroll
    for (int ct = 0; ct < 2; ++ct)
      #pragma unroll
      for (int r = 0; r < 4; ++r)
        sq[ct][r] = fmaxf(accq[nt][ct][r] + qb[ct], 0.f) * INVS;
    #pragma unroll
    for (int r = 0; r < 4; ++r) {
      float m = fmaxf(sq[0][r], sq[1][r]);
      m = fmaxf(m, __shfl_xor(m, 1)); m = fmaxf(m, __shfl_xor(m, 2));
      m = fmaxf(m, __shfl_xor(m, 4)); m = fmaxf(m, __shfl_xor(m, 8));
      float e0 = __expf(sq[0][r] - m), e1 = __expf(sq[1][r] - m);
      float s = e0 + e1;
      s += __shfl_xor(s, 1); s += __shfl_xor(s, 2);
      s += __shfl_xor(s, 4); s += __shfl_xor(s, 8);
      float inv = 1.f / s;
      accq[nt][0][r] = e0 * inv; accq[nt][1][r] = e1 * inv;
    }
    #pragma unroll
    for (int ct = 0; ct < 2; ++ct)
      #pragma unroll
      for (int r = 0; r < 4; ++r)
        accv[nt][ct][r] = fmaxf(accv[nt][ct][r] + vb[ct], 0.f);
  }

  // Q -> LDS -> coalesced global (bf16 [b][n][128])
  __syncthreads();
  #pragma unroll
  for (int nt = 0; nt < 2; ++nt)
    #pragma unroll
    for (int ct = 0; ct < 2; ++ct)
      #pragma unroll
      for (int r = 0; r < 4; ++r)
        XT[16*nt + 4*quad + r][32*wv + 16*ct + l16] = f2b(accq[nt][ct][r]);
  __syncthreads();
  #pragma unroll
  for (int j = 0; j < 2; ++j) {
    int id = tid + 256 * j; int n = id >> 4; int u = id & 15;
    *(uint4*)(QsT + (size_t)(b * 2048 + n0 + n) * 128 + 8 * u) = *(uint4*)&XT[n][8 * u];
  }
  __syncthreads();
  #pragma unroll
  for (int nt = 0; nt < 2; ++nt)
    #pragma unroll
    for (int ct = 0; ct < 2; ++ct)
      #pragma unroll
      for (int r = 0; r < 4; ++r)
        XT[16*nt + 4*quad + r][32*wv + 16*ct + l16] = f2b(accv[nt][ct][r]);
  __syncthreads();
  #pragma unroll
  for (int j = 0; j < 2; ++j) {
    int id = tid + 256 * j; int n = id >> 4; int u = id & 15;
    *(uint4*)(VT + (size_t)(b * 2048 + n0 + n) * 128 + 8 * u) = *(uint4*)&XT[n][8 * u];
  }
}

// ---------------------------------------------------------------------------
// k2_kv: kv[b,h,x,y] = sum_n keys[h,n,x] * V[b,h,n,y]; stored as [b][h][y][x]
// grid 64*16 = 1024 x 256; block handles 128 nodes, atomicAdd partials
// ---------------------------------------------------------------------------
__global__ __launch_bounds__(256) void k2_kv(const float* __restrict__ keys,
    const ushort_t* __restrict__ VT, float* __restrict__ kvws)
{
  int bid = blockIdx.x; int b = bid >> 4; int n0 = (bid & 15) * 128;
  int tid = threadIdx.x;
  int h = tid >> 6; int t64 = tid & 63; int a = t64 >> 3; int bg = t64 & 7;
  __shared__ __align__(16) float K_lds[32][132];
  __shared__ __align__(16) float V_lds[32][132];
  f32x4 zero4 = {0.f,0.f,0.f,0.f};
  f32x4 acc[4];
  #pragma unroll
  for (int i = 0; i < 4; ++i) acc[i] = zero4;
  for (int sub = 0; sub < 4; ++sub) {
    int nb = n0 + 32 * sub;
    #pragma unroll
    for (int p = 0; p < 4; ++p) {
      int id = tid + 256 * p; int nl = id >> 5; int q4 = id & 31; int c = 4 * q4;
      int hh = c >> 5; int xx = c & 31;
      *(float4*)&K_lds[nl][c] = *(const float4*)(keys + (size_t)(hh * 2048 + nb + nl) * 32 + xx);
    }
    #pragma unroll
    for (int p = 0; p < 2; ++p) {
      int id = tid + 256 * p; int nl = id >> 4; int g = id & 15;
      U16x8 raw; raw.u = *(const uint4*)(VT + (size_t)(b * 2048 + nb + nl) * 128 + 8 * g);
      float4 lo = { b2f(raw.s[0]), b2f(raw.s[1]), b2f(raw.s[2]), b2f(raw.s[3]) };
      float4 hi = { b2f(raw.s[4]), b2f(raw.s[5]), b2f(raw.s[6]), b2f(raw.s[7]) };
      *(float4*)&V_lds[nl][8 * g]     = lo;
      *(float4*)&V_lds[nl][8 * g + 4] = hi;
    }
    __syncthreads();
    #pragma unroll 4
    for (int nl = 0; nl < 32; ++nl) {
      f32x4 kx = *(const f32x4*)&K_lds[nl][h * 32 + 4 * a];
      f32x4 vy = *(const f32x4*)&V_lds[nl][h * 32 + 4 * bg];
      acc[0] += kx[0] * vy; acc[1] += kx[1] * vy;
      acc[2] += kx[2] * vy; acc[3] += kx[3] * vy;
    }
    __syncthreads();
  }
  #pragma unroll
  for (int i = 0; i < 4; ++i)
    #pragma unroll
    for (int j = 0; j < 4; ++j)
      atomicAdd(kvws + (size_t)((b * 4 + h) * 32 + 4 * bg + j) * 32 + 4 * a + i, acc[i][j]);
}

// ---------------------------------------------------------------------------
// k3_out: attn_qkv (block-diag GEMM, K=32/head) + Ws*V + bias_dyn -> MID(LDS),
// then final conv GEMM + relu + affine residual. Block: 64 nodes of one b.
// grid 64*32 = 2048 x 256; wave w owns head w / c_out group w.
// V & bias_dyn staged via LDS (coalesced) to avoid divergent scalar loads.
// ---------------------------------------------------------------------------
__global__ __launch_bounds__(256) void k3_out(const ushort_t* __restrict__ QsT,
    const ushort_t* __restrict__ VT, const float* __restrict__ kvws,
    const float* __restrict__ bias_dyn, const ushort_t* __restrict__ wcb,
    const float* __restrict__ cbias, const float* __restrict__ wpool,
    const float* __restrict__ aff_w, const float* __restrict__ aff_b,
    float* __restrict__ out)
{
  int bid = blockIdx.x; int b = bid >> 5; int n0 = (bid & 31) * 64;
  int tid = threadIdx.x; int wv = tid >> 6; int lane = tid & 63;
  int quad = lane >> 4; int l16 = lane & 15;
  __shared__ __align__(16) ushort_t kvT[4][32][40];   // [h][y][x] bf16, padded
  __shared__ __align__(16) ushort_t MID[64][136];
  __shared__ __align__(16) ushort_t VL[64][132];      // V tile, bf16
  __shared__ __align__(16) float    BD[64][36];       // bias_dyn tile

  float Ws = 0.f;
  #pragma unroll
  for (int i = 0; i < 9; ++i) Ws += wpool[i];

  uint4 wc[2][4];
  #pragma unroll
  for (int mt = 0; mt < 2; ++mt)
    #pragma unroll
    for (int k0 = 0; k0 < 4; ++k0)
      wc[mt][k0] = *(const uint4*)(wcb + (32 * wv + 16 * mt + l16) * 128 + 32 * k0 + 8 * quad);

  #pragma unroll
  for (int p = 0; p < 16; ++p) {
    int id = tid + 256 * p;
    kvT[id >> 10][(id >> 5) & 31][id & 31] = f2b(kvws[(size_t)b * 4096 + id]);
  }
  #pragma unroll
  for (int p = 0; p < 4; ++p) {        // V tile: 64 rows x 128 cols bf16
    int id = tid + 256 * p; int n = id >> 4; int u = id & 15;
    *(uint4*)&VL[n][8 * u] = *(const uint4*)(VT + (size_t)(b * 2048 + n0 + n) * 128 + 8 * u);
  }
  #pragma unroll
  for (int p = 0; p < 2; ++p) {        // bias_dyn tile: 64 rows x 32
    int id = tid + 256 * p; int n = id >> 3; int g = id & 7;
    *(float4*)&BD[n][4 * g] = *(const float4*)(bias_dyn + (size_t)(n0 + n) * 32 + 4 * g);
  }
  __syncthreads();

  f32x4 zero4 = {0.f,0.f,0.f,0.f};
  f32x4 acc1[4][2];
  #pragma unroll
  for (int nt = 0; nt < 4; ++nt) { acc1[nt][0] = zero4; acc1[nt][1] = zero4; }
  #pragma unroll
  for (int nt = 0; nt < 4; ++nt) {
    bf16x8 aq = *(const bf16x8*)(QsT + (size_t)(b * 2048 + n0 + 16 * nt + l16) * 128 + 32 * wv + 8 * quad);
    #pragma unroll
    for (int ct = 0; ct < 2; ++ct)
      acc1[nt][ct] = __builtin_amdgcn_mfma_f32_16x16x32_bf16(
          aq, *(const bf16x8*)&kvT[wv][16 * ct + l16][8 * quad], acc1[nt][ct], 0, 0, 0);
  }

  // epilogue 1: MID = attn_qkv + Ws*V + bias_dyn (bf16 in LDS)
  #pragma unroll
  for (int nt = 0; nt < 4; ++nt)
    #pragma unroll
    for (int ct = 0; ct < 2; ++ct)
      #pragma unroll
      for (int r = 0; r < 4; ++r) {
        int nl = 16 * nt + 4 * quad + r;
        int cc = 32 * wv + 16 * ct + l16;
        float v = b2f(VL[nl][cc]);
        float bd = BD[nl][16 * ct + l16];
        MID[nl][cc] = f2b(acc1[nt][ct][r] + Ws * v + bd);
      }
  __syncthreads();

  f32x4 acc2[2][4];
  #pragma unroll
  for (int mt = 0; mt < 2; ++mt)
    #pragma unroll
    for (int nt = 0; nt < 4; ++nt) acc2[mt][nt] = zero4;
  #pragma unroll
  for (int k0 = 0; k0 < 4; ++k0) {
    bf16x8 bb[4];
    #pragma unroll
    for (int nt = 0; nt < 4; ++nt)
      bb[nt] = *(const bf16x8*)&MID[16 * nt + l16][32 * k0 + 8 * quad];
    #pragma unroll
    for (int mt = 0; mt < 2; ++mt)
      #pragma unroll
      for (int nt = 0; nt < 4; ++nt)
        acc2[mt][nt] = __builtin_amdgcn_mfma_f32_16x16x32_bf16(
            as_bf16x8(wc[mt][k0]), bb[nt], acc2[mt][nt], 0, 0, 0);
  }

  // epilogue 2: relu(+cb), affine residual, store fp32
  #pragma unroll
  for (int mt = 0; mt < 2; ++mt)
    #pragma unroll
    for (int nt = 0; nt < 4; ++nt)
      #pragma unroll
      for (int r = 0; r < 4; ++r) {
        int c_out = 32 * wv + 16 * mt + 4 * quad + r;
        int nn2 = n0 + 16 * nt + l16;
        float yv = fmaxf(acc2[mt][nt][r] + cbias[c_out], 0.f);
        size_t ai = (size_t)c_out * 2048 + nn2;
        float awv = aff_w[ai], abv = aff_b[ai];
        out[(size_t)(b * 128 + c_out) * 2048 + nn2] = yv * awv + abv + yv;
      }
}

// ---------------------------------------------------------------------------
extern "C" void kernel_launch(void* const* d_in, const int* in_sizes, int n_in,
                              void* d_out, int out_size, void* d_ws, size_t ws_size,
                              hipStream_t stream)
{
  const float* x      = (const float*)d_in[0];
  const float* qw     = (const float*)d_in[1];
  const float* qb     = (const float*)d_in[2];
  const float* vw     = (const float*)d_in[3];
  const float* vb     = (const float*)d_in[4];
  const float* cw     = (const float*)d_in[5];
  const float* cb     = (const float*)d_in[6];
  const float* memory = (const float*)d_in[7];
  const float* nv1    = (const float*)d_in[8];
  const float* nv2    = (const float*)d_in[9];
  const float* wpool  = (const float*)d_in[10];
  const float* bpool  = (const float*)d_in[11];
  const float* aw     = (const float*)d_in[12];
  const float* ab     = (const float*)d_in[13];
  float* out = (float*)d_out;

  char* ws = (char*)d_ws;
  ushort_t* QsT      = (ushort_t*)(ws);                 // 33,554,432 B
  ushort_t* VT       = (ushort_t*)(ws + 33554432);      // 33,554,432 B
  float*    kvws     = (float*)   (ws + 67108864);      //  1,048,576 B
  float*    keys     = (float*)   (ws + 68157440);      //  1,048,576 B
  float*    bias_dyn = (float*)   (ws + 69206016);      //    262,144 B
  ushort_t* wqb      = (ushort_t*)(ws + 69468160);      //     32,768 B
  ushort_t* wvb      = (ushort_t*)(ws + 69500928);      //     32,768 B
  ushort_t* wcb      = (ushort_t*)(ws + 69533696);      //     32,768 B
  ushort_t* Ebuf     = (ushort_t*)(ws + 69566464);      //  8,388,608 B
  ushort_t* bpT      = (ushort_t*)(ws + 77955072);      //    131,072 B (end 78,086,144)

  k0_prep<<<256, 256, 0, stream>>>(qw, vw, cw, memory, bpool, wqb, wvb, wcb,
                                   keys, kvws, bias_dyn, bpT);
  kb1<<<2048, 256, 0, stream>>>(nv1, nv2, Ebuf);
  kb2<<<128, 256, 0, stream>>>(Ebuf, bpT, bias_dyn);
  k1_qv<<<4096, 256, 0, stream>>>(x, wqb, wvb, qb, vb, QsT, VT);
  k2_kv<<<1024, 256, 0, stream>>>(keys, VT, kvws);
  k3_out<<<2048, 256, 0, stream>>>(QsT, VT, kvws, bias_dyn, wcb, cb, wpool, aw, ab, out);
}

// Round 3
// 225.749 us; speedup vs baseline: 1.4937x; 1.2100x over previous
//
#include <hip/hip_runtime.h>

#define NB 64
#define CH 128
#define NNODE 2048
#define NH 4
#define DKK 32
#define INVS 0.17677669529663687f

typedef __bf16 bf16x8 __attribute__((ext_vector_type(8)));
typedef float f32x4 __attribute__((ext_vector_type(4)));
typedef unsigned short ushort_t;

union U16x8 { uint4 u; bf16x8 b; unsigned short s[8]; };

__device__ inline bf16x8 as_bf16x8(uint4 u){ U16x8 x; x.u = u; return x.b; }
__device__ inline unsigned short f2b(float f){ __bf16 h = (__bf16)f; return __builtin_bit_cast(unsigned short, h); }
__device__ inline float b2f(unsigned short u){ __bf16 h = __builtin_bit_cast(__bf16, u); return (float)h; }

// ---------------------------------------------------------------------------
// k0_prep: weights->bf16, key softmax -> keysT bf16 [h][x][n], zero bias_dyn,
// build bpT [32][2048]. grid 256 x 256  (gid < 65536)
// ---------------------------------------------------------------------------
__global__ __launch_bounds__(256) void k0_prep(const float* __restrict__ qw,
    const float* __restrict__ vw, const float* __restrict__ cw,
    const float* __restrict__ memory, const float* __restrict__ bias_pool,
    ushort_t* __restrict__ wqb, ushort_t* __restrict__ wvb, ushort_t* __restrict__ wcb,
    ushort_t* __restrict__ keysT, float* __restrict__ bias_dyn,
    ushort_t* __restrict__ bpT)
{
  int gid = blockIdx.x * 256 + threadIdx.x;
  if (gid < 16384) { wqb[gid] = f2b(qw[gid]); wvb[gid] = f2b(vw[gid]); wcb[gid] = f2b(cw[gid]); }
  bias_dyn[gid] = 0.f;                               // 2048*32 = 65536 == grid*block
  { int k = gid >> 11, m = gid & 2047;               // bpT[k][m] = bias_pool[m][k]
    bpT[gid] = f2b(bias_pool[m * 32 + k]); }
  if (gid < 8192) {  // one row (h,n) of 32: softmax(memory * invscale) -> keysT
    int h = gid >> 11, n = gid & 2047;
    const float* src = memory + (size_t)gid * 32;
    float v[32]; float m = -1e30f;
    #pragma unroll
    for (int i = 0; i < 32; ++i) { v[i] = src[i] * INVS; m = fmaxf(m, v[i]); }
    float s = 0.f;
    #pragma unroll
    for (int i = 0; i < 32; ++i) { v[i] = __expf(v[i] - m); s += v[i]; }
    float inv = 1.f / s;
    #pragma unroll
    for (int i = 0; i < 32; ++i)   // coalesced across n per instruction
      keysT[(size_t)(h * 32 + i) * 2048 + n] = f2b(v[i] * inv);
  }
}

// ---------------------------------------------------------------------------
// kb1: normalized softmax rows of relu(nv1@nv2) -> Ebuf bf16 [2048][2048]
// grid 2048 (one block per row n) x 256; fully coalesced nv2 reads
// ---------------------------------------------------------------------------
__global__ __launch_bounds__(256) void kb1(const float* __restrict__ nv1,
    const float* __restrict__ nv2, ushort_t* __restrict__ Ebuf)
{
  int n = blockIdx.x; int tid = threadIdx.x;
  float a1[10];
  #pragma unroll
  for (int d = 0; d < 10; ++d) a1[d] = nv1[n * 10 + d];
  int m0 = tid * 8;
  float s[8];
  #pragma unroll
  for (int j = 0; j < 8; ++j) s[j] = 0.f;
  #pragma unroll
  for (int d = 0; d < 10; ++d) {
    const float* p = nv2 + d * 2048 + m0;
    float4 u = *(const float4*)p; float4 v = *(const float4*)(p + 4);
    s[0] += a1[d] * u.x; s[1] += a1[d] * u.y; s[2] += a1[d] * u.z; s[3] += a1[d] * u.w;
    s[4] += a1[d] * v.x; s[5] += a1[d] * v.y; s[6] += a1[d] * v.z; s[7] += a1[d] * v.w;
  }
  float e[8]; float sum = 0.f;
  #pragma unroll
  for (int j = 0; j < 8; ++j) { e[j] = __expf(fmaxf(s[j], 0.f)); sum += e[j]; }
  #pragma unroll
  for (int d = 1; d < 64; d <<= 1) sum += __shfl_xor(sum, d);
  __shared__ float red[4];
  if ((tid & 63) == 0) red[tid >> 6] = sum;
  __syncthreads();
  float inv = 1.f / (red[0] + red[1] + red[2] + red[3]);
  U16x8 o;
  #pragma unroll
  for (int j = 0; j < 8; ++j) o.s[j] = f2b(e[j] * inv);
  *(uint4*)(Ebuf + (size_t)n * 2048 + m0) = o.u;
}

// ---------------------------------------------------------------------------
// kb2: bias_dyn = Ebuf @ bias_pool via MFMA. M=2048,N=32,K=2048, 8-way K-split
// grid 128 x 256; atomicAdd fp32 partials (bias_dyn zeroed by k0_prep)
// ---------------------------------------------------------------------------
__global__ __launch_bounds__(256) void kb2(const ushort_t* __restrict__ Ebuf,
    const ushort_t* __restrict__ bpT, float* __restrict__ bias_dyn)
{
  int bid = blockIdx.x;
  int n0 = (bid >> 3) * 128;
  int m0 = (bid & 7) * 256;
  int tid = threadIdx.x; int wv = tid >> 6; int lane = tid & 63;
  int quad = lane >> 4; int l16 = lane & 15;
  int r0 = n0 + 32 * wv;
  f32x4 zero4 = {0.f,0.f,0.f,0.f};
  f32x4 acc[2][2];
  acc[0][0] = zero4; acc[0][1] = zero4; acc[1][0] = zero4; acc[1][1] = zero4;
  for (int ks = 0; ks < 256; ks += 32) {
    int mb = m0 + ks + 8 * quad;
    bf16x8 a0 = *(const bf16x8*)(Ebuf + (size_t)(r0 + l16) * 2048 + mb);
    bf16x8 a1 = *(const bf16x8*)(Ebuf + (size_t)(r0 + 16 + l16) * 2048 + mb);
    bf16x8 b0 = *(const bf16x8*)(bpT + (size_t)l16 * 2048 + mb);
    bf16x8 b1 = *(const bf16x8*)(bpT + (size_t)(16 + l16) * 2048 + mb);
    acc[0][0] = __builtin_amdgcn_mfma_f32_16x16x32_bf16(a0, b0, acc[0][0], 0, 0, 0);
    acc[0][1] = __builtin_amdgcn_mfma_f32_16x16x32_bf16(a0, b1, acc[0][1], 0, 0, 0);
    acc[1][0] = __builtin_amdgcn_mfma_f32_16x16x32_bf16(a1, b0, acc[1][0], 0, 0, 0);
    acc[1][1] = __builtin_amdgcn_mfma_f32_16x16x32_bf16(a1, b1, acc[1][1], 0, 0, 0);
  }
  #pragma unroll
  for (int rt = 0; rt < 2; ++rt)
    #pragma unroll
    for (int ct = 0; ct < 2; ++ct)
      #pragma unroll
      for (int r = 0; r < 4; ++r)
        atomicAdd(bias_dyn + (size_t)(r0 + 16*rt + 4*quad + r) * 32 + 16*ct + l16,
                  acc[rt][ct][r]);
}

// ---------------------------------------------------------------------------
// k1_qv: Q = softmax_head(relu(Wq x)/scale), V = relu(Wv x); stores QsT,VT as
// bf16 [b][n][128]. Block: 32 nodes of one b; wave w owns head w (32 chans).
// grid 64*64 = 4096 x 256
// ---------------------------------------------------------------------------
__global__ __launch_bounds__(256) void k1_qv(const float* __restrict__ x,
    const ushort_t* __restrict__ wqb, const ushort_t* __restrict__ wvb,
    const float* __restrict__ qbias, const float* __restrict__ vbias,
    ushort_t* __restrict__ QsT, ushort_t* __restrict__ VT)
{
  int bid = blockIdx.x; int b = bid >> 6; int n0 = (bid & 63) * 32;
  int tid = threadIdx.x; int wv = tid >> 6; int lane = tid & 63;
  int quad = lane >> 4; int l16 = lane & 15;
  __shared__ __align__(16) ushort_t XT[32][136];   // 8.7 KB, reused as out buffer

  // cache W B-frags in registers: B[k=c][col=o] = W[o][c], 8 contiguous c / lane
  uint4 wq[2][4], wvv[2][4];
  #pragma unroll
  for (int ct = 0; ct < 2; ++ct)
    #pragma unroll
    for (int k0 = 0; k0 < 4; ++k0) {
      int off = (32 * wv + 16 * ct + l16) * 128 + 32 * k0 + 8 * quad;
      wq[ct][k0]  = *(const uint4*)(wqb + off);
      wvv[ct][k0] = *(const uint4*)(wvb + off);
    }
  float qb[2], vb[2];
  #pragma unroll
  for (int ct = 0; ct < 2; ++ct) {
    qb[ct] = qbias[32 * wv + 16 * ct + l16];
    vb[ct] = vbias[32 * wv + 16 * ct + l16];
  }

  // stage X tile [128 c][32 n] fp32 -> XT[n][c] bf16 (transpose)
  #pragma unroll
  for (int p = 0; p < 4; ++p) {
    int c = 32 * p + (tid >> 3); int i = tid & 7;
    float4 v4 = *(const float4*)(x + (size_t)(b * 128 + c) * 2048 + n0 + 4 * i);
    XT[4*i+0][c] = f2b(v4.x); XT[4*i+1][c] = f2b(v4.y);
    XT[4*i+2][c] = f2b(v4.z); XT[4*i+3][c] = f2b(v4.w);
  }
  __syncthreads();

  f32x4 zero4 = {0.f,0.f,0.f,0.f};
  f32x4 accq[2][2], accv[2][2];
  #pragma unroll
  for (int i = 0; i < 2; ++i)
    #pragma unroll
    for (int j = 0; j < 2; ++j) { accq[i][j] = zero4; accv[i][j] = zero4; }

  #pragma unroll
  for (int k0 = 0; k0 < 4; ++k0) {
    bf16x8 a0 = *(const bf16x8*)&XT[l16][32 * k0 + 8 * quad];
    bf16x8 a1 = *(const bf16x8*)&XT[16 + l16][32 * k0 + 8 * quad];
    #pragma unroll
    for (int ct = 0; ct < 2; ++ct) {
      accq[0][ct] = __builtin_amdgcn_mfma_f32_16x16x32_bf16(a0, as_bf16x8(wq[ct][k0]),  accq[0][ct], 0, 0, 0);
      accq[1][ct] = __builtin_amdgcn_mfma_f32_16x16x32_bf16(a1, as_bf16x8(wq[ct][k0]),  accq[1][ct], 0, 0, 0);
      accv[0][ct] = __builtin_amdgcn_mfma_f32_16x16x32_bf16(a0, as_bf16x8(wvv[ct][k0]), accv[0][ct], 0, 0, 0);
      accv[1][ct] = __builtin_amdgcn_mfma_f32_16x16x32_bf16(a1, as_bf16x8(wvv[ct][k0]), accv[1][ct], 0, 0, 0);
    }
  }

  // epilogue: relu(+bias); query softmax over the head's 32 channels per n-row
  #pragma unroll
  for (int nt = 0; nt < 2; ++nt) {
    float sq[2][4];
    #pragma unroll
    for (int ct = 0; ct < 2; ++ct)
      #pragma unroll
      for (int r = 0; r < 4; ++r)
        sq[ct][r] = fmaxf(accq[nt][ct][r] + qb[ct], 0.f) * INVS;
    #pragma unroll
    for (int r = 0; r < 4; ++r) {
      float m = fmaxf(sq[0][r], sq[1][r]);
      m = fmaxf(m, __shfl_xor(m, 1)); m = fmaxf(m, __shfl_xor(m, 2));
      m = fmaxf(m, __shfl_xor(m, 4)); m = fmaxf(m, __shfl_xor(m, 8));
      float e0 = __expf(sq[0][r] - m), e1 = __expf(sq[1][r] - m);
      float s = e0 + e1;
      s += __shfl_xor(s, 1); s += __shfl_xor(s, 2);
      s += __shfl_xor(s, 4); s += __shfl_xor(s, 8);
      float inv = 1.f / s;
      accq[nt][0][r] = e0 * inv; accq[nt][1][r] = e1 * inv;
    }
    #pragma unroll
    for (int ct = 0; ct < 2; ++ct)
      #pragma unroll
      for (int r = 0; r < 4; ++r)
        accv[nt][ct][r] = fmaxf(accv[nt][ct][r] + vb[ct], 0.f);
  }

  // Q -> LDS -> coalesced global (bf16 [b][n][128])
  __syncthreads();
  #pragma unroll
  for (int nt = 0; nt < 2; ++nt)
    #pragma unroll
    for (int ct = 0; ct < 2; ++ct)
      #pragma unroll
      for (int r = 0; r < 4; ++r)
        XT[16*nt + 4*quad + r][32*wv + 16*ct + l16] = f2b(accq[nt][ct][r]);
  __syncthreads();
  #pragma unroll
  for (int j = 0; j < 2; ++j) {
    int id = tid + 256 * j; int n = id >> 4; int u = id & 15;
    *(uint4*)(QsT + (size_t)(b * 2048 + n0 + n) * 128 + 8 * u) = *(uint4*)&XT[n][8 * u];
  }
  __syncthreads();
  #pragma unroll
  for (int nt = 0; nt < 2; ++nt)
    #pragma unroll
    for (int ct = 0; ct < 2; ++ct)
      #pragma unroll
      for (int r = 0; r < 4; ++r)
        XT[16*nt + 4*quad + r][32*wv + 16*ct + l16] = f2b(accv[nt][ct][r]);
  __syncthreads();
  #pragma unroll
  for (int j = 0; j < 2; ++j) {
    int id = tid + 256 * j; int n = id >> 4; int u = id & 15;
    *(uint4*)(VT + (size_t)(b * 2048 + n0 + n) * 128 + 8 * u) = *(uint4*)&XT[n][8 * u];
  }
}

// ---------------------------------------------------------------------------
// k2_kv: per-(b,h) GEMM kv[x][y] = sum_n keysT[h][x][n] * V[n][h*32+y] via
// MFMA. grid 512 = (b x 8 n-splits of 256) x 256; wave = head.
// Writes per-block partials (NO atomics) -> kvp[bid][h][y][x].
// ---------------------------------------------------------------------------
__global__ __launch_bounds__(256) void k2_kv(const ushort_t* __restrict__ keysT,
    const ushort_t* __restrict__ VT, float* __restrict__ kvp)
{
  int bid = blockIdx.x; int b = bid >> 3; int nb = (bid & 7) * 256;
  int tid = threadIdx.x; int wv = tid >> 6; int lane = tid & 63;
  int quad = lane >> 4; int l16 = lane & 15;
  __shared__ __align__(16) ushort_t Vraw[128][136];   // 34.8 KB

  f32x4 zero4 = {0.f,0.f,0.f,0.f};
  f32x4 acc[2][2];
  acc[0][0] = zero4; acc[0][1] = zero4; acc[1][0] = zero4; acc[1][1] = zero4;

  for (int chunk = 0; chunk < 2; ++chunk) {
    int nc = nb + 128 * chunk;
    if (chunk) __syncthreads();
    #pragma unroll
    for (int p = 0; p < 8; ++p) {
      int id = tid + 256 * p; int n = id >> 4; int g = id & 15;
      *(uint4*)&Vraw[n][8 * g] = *(const uint4*)(VT + (size_t)(b * 2048 + nc + n) * 128 + 8 * g);
    }
    __syncthreads();
    const ushort_t* kT = keysT + (size_t)(wv * 32) * 2048 + nc;
    #pragma unroll
    for (int ks = 0; ks < 4; ++ks) {
      int k0 = 32 * ks + 8 * quad;
      bf16x8 a0 = *(const bf16x8*)(kT + (size_t)l16 * 2048 + k0);
      bf16x8 a1 = *(const bf16x8*)(kT + (size_t)(16 + l16) * 2048 + k0);
      U16x8 b0, b1;
      #pragma unroll
      for (int j = 0; j < 8; ++j) {
        b0.s[j] = Vraw[k0 + j][32 * wv + l16];
        b1.s[j] = Vraw[k0 + j][32 * wv + 16 + l16];
      }
      acc[0][0] = __builtin_amdgcn_mfma_f32_16x16x32_bf16(a0, b0.b, acc[0][0], 0, 0, 0);
      acc[0][1] = __builtin_amdgcn_mfma_f32_16x16x32_bf16(a0, b1.b, acc[0][1], 0, 0, 0);
      acc[1][0] = __builtin_amdgcn_mfma_f32_16x16x32_bf16(a1, b0.b, acc[1][0], 0, 0, 0);
      acc[1][1] = __builtin_amdgcn_mfma_f32_16x16x32_bf16(a1, b1.b, acc[1][1], 0, 0, 0);
    }
  }

  float* dst = kvp + (size_t)bid * 4096 + wv * 1024;   // [bid][h][y][x]
  #pragma unroll
  for (int yt = 0; yt < 2; ++yt)
    #pragma unroll
    for (int xt = 0; xt < 2; ++xt)
      #pragma unroll
      for (int r = 0; r < 4; ++r)
        dst[(16 * yt + l16) * 32 + 16 * xt + 4 * quad + r] = acc[xt][yt][r];
}

// ---------------------------------------------------------------------------
// kred: kvws[b][i] = sum over 8 n-split partials. grid 1024 x 256, coalesced.
// ---------------------------------------------------------------------------
__global__ __launch_bounds__(256) void kred(const float* __restrict__ kvp,
    float* __restrict__ kvws)
{
  int gid = blockIdx.x * 256 + threadIdx.x;   // 262144 outputs
  int b = gid >> 12; int i = gid & 4095;
  const float* p = kvp + (size_t)(b * 8) * 4096 + i;
  float s = 0.f;
  #pragma unroll
  for (int t = 0; t < 8; ++t) s += p[t * 4096];
  kvws[gid] = s;
}

// ---------------------------------------------------------------------------
// k3_out: attn_qkv (block-diag GEMM, K=32/head) + Ws*V + bias_dyn -> MID(LDS),
// then final conv GEMM + relu + affine residual. Block: 64 nodes of one b.
// grid 64*32 = 2048 x 256; wave w owns head w / c_out group w.
// ---------------------------------------------------------------------------
__global__ __launch_bounds__(256) void k3_out(const ushort_t* __restrict__ QsT,
    const ushort_t* __restrict__ VT, const float* __restrict__ kvws,
    const float* __restrict__ bias_dyn, const ushort_t* __restrict__ wcb,
    const float* __restrict__ cbias, const float* __restrict__ wpool,
    const float* __restrict__ aff_w, const float* __restrict__ aff_b,
    float* __restrict__ out)
{
  int bid = blockIdx.x; int b = bid >> 5; int n0 = (bid & 31) * 64;
  int tid = threadIdx.x; int wv = tid >> 6; int lane = tid & 63;
  int quad = lane >> 4; int l16 = lane & 15;
  __shared__ __align__(16) ushort_t kvT[4][32][40];   // [h][y][x] bf16, padded
  __shared__ __align__(16) ushort_t MID[64][136];
  __shared__ __align__(16) ushort_t VL[64][132];      // V tile, bf16
  __shared__ __align__(16) float    BD[64][36];       // bias_dyn tile

  float Ws = 0.f;
  #pragma unroll
  for (int i = 0; i < 9; ++i) Ws += wpool[i];

  uint4 wc[2][4];
  #pragma unroll
  for (int mt = 0; mt < 2; ++mt)
    #pragma unroll
    for (int k0 = 0; k0 < 4; ++k0)
      wc[mt][k0] = *(const uint4*)(wcb + (32 * wv + 16 * mt + l16) * 128 + 32 * k0 + 8 * quad);

  #pragma unroll
  for (int p = 0; p < 16; ++p) {
    int id = tid + 256 * p;
    kvT[id >> 10][(id >> 5) & 31][id & 31] = f2b(kvws[(size_t)b * 4096 + id]);
  }
  #pragma unroll
  for (int p = 0; p < 4; ++p) {        // V tile: 64 rows x 128 cols bf16
    int id = tid + 256 * p; int n = id >> 4; int u = id & 15;
    *(uint4*)&VL[n][8 * u] = *(const uint4*)(VT + (size_t)(b * 2048 + n0 + n) * 128 + 8 * u);
  }
  #pragma unroll
  for (int p = 0; p < 2; ++p) {        // bias_dyn tile: 64 rows x 32
    int id = tid + 256 * p; int n = id >> 3; int g = id & 7;
    *(float4*)&BD[n][4 * g] = *(const float4*)(bias_dyn + (size_t)(n0 + n) * 32 + 4 * g);
  }
  __syncthreads();

  f32x4 zero4 = {0.f,0.f,0.f,0.f};
  f32x4 acc1[4][2];
  #pragma unroll
  for (int nt = 0; nt < 4; ++nt) { acc1[nt][0] = zero4; acc1[nt][1] = zero4; }
  #pragma unroll
  for (int nt = 0; nt < 4; ++nt) {
    bf16x8 aq = *(const bf16x8*)(QsT + (size_t)(b * 2048 + n0 + 16 * nt + l16) * 128 + 32 * wv + 8 * quad);
    #pragma unroll
    for (int ct = 0; ct < 2; ++ct)
      acc1[nt][ct] = __builtin_amdgcn_mfma_f32_16x16x32_bf16(
          aq, *(const bf16x8*)&kvT[wv][16 * ct + l16][8 * quad], acc1[nt][ct], 0, 0, 0);
  }

  // epilogue 1: MID = attn_qkv + Ws*V + bias_dyn (bf16 in LDS)
  #pragma unroll
  for (int nt = 0; nt < 4; ++nt)
    #pragma unroll
    for (int ct = 0; ct < 2; ++ct)
      #pragma unroll
      for (int r = 0; r < 4; ++r) {
        int nl = 16 * nt + 4 * quad + r;
        int cc = 32 * wv + 16 * ct + l16;
        float v = b2f(VL[nl][cc]);
        float bd = BD[nl][16 * ct + l16];
        MID[nl][cc] = f2b(acc1[nt][ct][r] + Ws * v + bd);
      }
  __syncthreads();

  f32x4 acc2[2][4];
  #pragma unroll
  for (int mt = 0; mt < 2; ++mt)
    #pragma unroll
    for (int nt = 0; nt < 4; ++nt) acc2[mt][nt] = zero4;
  #pragma unroll
  for (int k0 = 0; k0 < 4; ++k0) {
    bf16x8 bb[4];
    #pragma unroll
    for (int nt = 0; nt < 4; ++nt)
      bb[nt] = *(const bf16x8*)&MID[16 * nt + l16][32 * k0 + 8 * quad];
    #pragma unroll
    for (int mt = 0; mt < 2; ++mt)
      #pragma unroll
      for (int nt = 0; nt < 4; ++nt)
        acc2[mt][nt] = __builtin_amdgcn_mfma_f32_16x16x32_bf16(
            as_bf16x8(wc[mt][k0]), bb[nt], acc2[mt][nt], 0, 0, 0);
  }

  // epilogue 2: relu(+cb), affine residual, store fp32
  #pragma unroll
  for (int mt = 0; mt < 2; ++mt)
    #pragma unroll
    for (int nt = 0; nt < 4; ++nt)
      #pragma unroll
      for (int r = 0; r < 4; ++r) {
        int c_out = 32 * wv + 16 * mt + 4 * quad + r;
        int nn2 = n0 + 16 * nt + l16;
        float yv = fmaxf(acc2[mt][nt][r] + cbias[c_out], 0.f);
        size_t ai = (size_t)c_out * 2048 + nn2;
        float awv = aff_w[ai], abv = aff_b[ai];
        out[(size_t)(b * 128 + c_out) * 2048 + nn2] = yv * awv + abv + yv;
      }
}

// ---------------------------------------------------------------------------
extern "C" void kernel_launch(void* const* d_in, const int* in_sizes, int n_in,
                              void* d_out, int out_size, void* d_ws, size_t ws_size,
                              hipStream_t stream)
{
  const float* x      = (const float*)d_in[0];
  const float* qw     = (const float*)d_in[1];
  const float* qb     = (const float*)d_in[2];
  const float* vw     = (const float*)d_in[3];
  const float* vb     = (const float*)d_in[4];
  const float* cw     = (const float*)d_in[5];
  const float* cb     = (const float*)d_in[6];
  const float* memory = (const float*)d_in[7];
  const float* nv1    = (const float*)d_in[8];
  const float* nv2    = (const float*)d_in[9];
  const float* wpool  = (const float*)d_in[10];
  const float* bpool  = (const float*)d_in[11];
  const float* aw     = (const float*)d_in[12];
  const float* ab     = (const float*)d_in[13];
  float* out = (float*)d_out;

  char* ws = (char*)d_ws;
  ushort_t* QsT      = (ushort_t*)(ws);                 // 33,554,432 B
  ushort_t* VT       = (ushort_t*)(ws + 33554432);      // 33,554,432 B
  float*    kvws     = (float*)   (ws + 67108864);      //  1,048,576 B
  ushort_t* keysT    = (ushort_t*)(ws + 68157440);      //    524,288 B (in old keys slot)
  float*    bias_dyn = (float*)   (ws + 69206016);      //    262,144 B
  ushort_t* wqb      = (ushort_t*)(ws + 69468160);      //     32,768 B
  ushort_t* wvb      = (ushort_t*)(ws + 69500928);      //     32,768 B
  ushort_t* wcb      = (ushort_t*)(ws + 69533696);      //     32,768 B
  ushort_t* Ebuf     = (ushort_t*)(ws + 69566464);      //  8,388,608 B
  ushort_t* bpT      = (ushort_t*)(ws + 77955072);      //    131,072 B (end 78,086,144)
  float*    kvp      = (float*)Ebuf;                    //  8,388,608 B (Ebuf dead after kb2)

  k0_prep<<<256, 256, 0, stream>>>(qw, vw, cw, memory, bpool, wqb, wvb, wcb,
                                   keysT, bias_dyn, bpT);
  kb1<<<2048, 256, 0, stream>>>(nv1, nv2, Ebuf);
  kb2<<<128, 256, 0, stream>>>(Ebuf, bpT, bias_dyn);
  k1_qv<<<4096, 256, 0, stream>>>(x, wqb, wvb, qb, vb, QsT, VT);
  k2_kv<<<512, 256, 0, stream>>>(keysT, VT, kvp);
  kred<<<1024, 256, 0, stream>>>(kvp, kvws);
  k3_out<<<2048, 256, 0, stream>>>(QsT, VT, kvws, bias_dyn, wcb, cb, wpool, aw, ab, out);
}

// Round 4
// 212.600 us; speedup vs baseline: 1.5860x; 1.0618x over previous
//
#include <hip/hip_runtime.h>

#define NB 64
#define CH 128
#define NNODE 2048
#define NH 4
#define DKK 32
#define INVS 0.17677669529663687f

typedef __bf16 bf16x8 __attribute__((ext_vector_type(8)));
typedef float f32x4 __attribute__((ext_vector_type(4)));
typedef unsigned short ushort_t;

union U16x8 { uint4 u; bf16x8 b; unsigned short s[8]; };
union U16x4 { uint2 u; unsigned short s[4]; };

__device__ inline bf16x8 as_bf16x8(uint4 u){ U16x8 x; x.u = u; return x.b; }
__device__ inline unsigned short f2b(float f){ __bf16 h = (__bf16)f; return __builtin_bit_cast(unsigned short, h); }
__device__ inline float b2f(unsigned short u){ __bf16 h = __builtin_bit_cast(__bf16, u); return (float)h; }

// ---------------------------------------------------------------------------
// k0_prep: weights->bf16, key softmax -> keysT bf16 [h][x][n], zero bias_dyn,
// build bpT [32][2048]. grid 256 x 256  (gid < 65536)
// ---------------------------------------------------------------------------
__global__ __launch_bounds__(256) void k0_prep(const float* __restrict__ qw,
    const float* __restrict__ vw, const float* __restrict__ cw,
    const float* __restrict__ memory, const float* __restrict__ bias_pool,
    ushort_t* __restrict__ wqb, ushort_t* __restrict__ wvb, ushort_t* __restrict__ wcb,
    ushort_t* __restrict__ keysT, float* __restrict__ bias_dyn,
    ushort_t* __restrict__ bpT)
{
  int gid = blockIdx.x * 256 + threadIdx.x;
  if (gid < 16384) { wqb[gid] = f2b(qw[gid]); wvb[gid] = f2b(vw[gid]); wcb[gid] = f2b(cw[gid]); }
  bias_dyn[gid] = 0.f;                               // 2048*32 = 65536 == grid*block
  { int k = gid >> 11, m = gid & 2047;               // bpT[k][m] = bias_pool[m][k]
    bpT[gid] = f2b(bias_pool[m * 32 + k]); }
  if (gid < 8192) {  // one row (h,n) of 32: softmax(memory * invscale) -> keysT
    int h = gid >> 11, n = gid & 2047;
    const float* src = memory + (size_t)gid * 32;
    float v[32]; float m = -1e30f;
    #pragma unroll
    for (int i = 0; i < 32; ++i) { v[i] = src[i] * INVS; m = fmaxf(m, v[i]); }
    float s = 0.f;
    #pragma unroll
    for (int i = 0; i < 32; ++i) { v[i] = __expf(v[i] - m); s += v[i]; }
    float inv = 1.f / s;
    #pragma unroll
    for (int i = 0; i < 32; ++i)   // coalesced across n per instruction
      keysT[(size_t)(h * 32 + i) * 2048 + n] = f2b(v[i] * inv);
  }
}

// ---------------------------------------------------------------------------
// kb1: normalized softmax rows of relu(nv1@nv2) -> Ebuf bf16 [2048][2048]
// grid 2048 (one block per row n) x 256; fully coalesced nv2 reads
// ---------------------------------------------------------------------------
__global__ __launch_bounds__(256) void kb1(const float* __restrict__ nv1,
    const float* __restrict__ nv2, ushort_t* __restrict__ Ebuf)
{
  int n = blockIdx.x; int tid = threadIdx.x;
  float a1[10];
  #pragma unroll
  for (int d = 0; d < 10; ++d) a1[d] = nv1[n * 10 + d];
  int m0 = tid * 8;
  float s[8];
  #pragma unroll
  for (int j = 0; j < 8; ++j) s[j] = 0.f;
  #pragma unroll
  for (int d = 0; d < 10; ++d) {
    const float* p = nv2 + d * 2048 + m0;
    float4 u = *(const float4*)p; float4 v = *(const float4*)(p + 4);
    s[0] += a1[d] * u.x; s[1] += a1[d] * u.y; s[2] += a1[d] * u.z; s[3] += a1[d] * u.w;
    s[4] += a1[d] * v.x; s[5] += a1[d] * v.y; s[6] += a1[d] * v.z; s[7] += a1[d] * v.w;
  }
  float e[8]; float sum = 0.f;
  #pragma unroll
  for (int j = 0; j < 8; ++j) { e[j] = __expf(fmaxf(s[j], 0.f)); sum += e[j]; }
  #pragma unroll
  for (int d = 1; d < 64; d <<= 1) sum += __shfl_xor(sum, d);
  __shared__ float red[4];
  if ((tid & 63) == 0) red[tid >> 6] = sum;
  __syncthreads();
  float inv = 1.f / (red[0] + red[1] + red[2] + red[3]);
  U16x8 o;
  #pragma unroll
  for (int j = 0; j < 8; ++j) o.s[j] = f2b(e[j] * inv);
  *(uint4*)(Ebuf + (size_t)n * 2048 + m0) = o.u;
}

// ---------------------------------------------------------------------------
// kb2: bias_dyn = Ebuf @ bias_pool via MFMA. M=2048,N=32,K=2048, 8-way K-split
// grid 128 x 256; atomicAdd fp32 partials (bias_dyn zeroed by k0_prep)
// ---------------------------------------------------------------------------
__global__ __launch_bounds__(256) void kb2(const ushort_t* __restrict__ Ebuf,
    const ushort_t* __restrict__ bpT, float* __restrict__ bias_dyn)
{
  int bid = blockIdx.x;
  int n0 = (bid >> 3) * 128;
  int m0 = (bid & 7) * 256;
  int tid = threadIdx.x; int wv = tid >> 6; int lane = tid & 63;
  int quad = lane >> 4; int l16 = lane & 15;
  int r0 = n0 + 32 * wv;
  f32x4 zero4 = {0.f,0.f,0.f,0.f};
  f32x4 acc[2][2];
  acc[0][0] = zero4; acc[0][1] = zero4; acc[1][0] = zero4; acc[1][1] = zero4;
  for (int ks = 0; ks < 256; ks += 32) {
    int mb = m0 + ks + 8 * quad;
    bf16x8 a0 = *(const bf16x8*)(Ebuf + (size_t)(r0 + l16) * 2048 + mb);
    bf16x8 a1 = *(const bf16x8*)(Ebuf + (size_t)(r0 + 16 + l16) * 2048 + mb);
    bf16x8 b0 = *(const bf16x8*)(bpT + (size_t)l16 * 2048 + mb);
    bf16x8 b1 = *(const bf16x8*)(bpT + (size_t)(16 + l16) * 2048 + mb);
    acc[0][0] = __builtin_amdgcn_mfma_f32_16x16x32_bf16(a0, b0, acc[0][0], 0, 0, 0);
    acc[0][1] = __builtin_amdgcn_mfma_f32_16x16x32_bf16(a0, b1, acc[0][1], 0, 0, 0);
    acc[1][0] = __builtin_amdgcn_mfma_f32_16x16x32_bf16(a1, b0, acc[1][0], 0, 0, 0);
    acc[1][1] = __builtin_amdgcn_mfma_f32_16x16x32_bf16(a1, b1, acc[1][1], 0, 0, 0);
  }
  #pragma unroll
  for (int rt = 0; rt < 2; ++rt)
    #pragma unroll
    for (int ct = 0; ct < 2; ++ct)
      #pragma unroll
      for (int r = 0; r < 4; ++r)
        atomicAdd(bias_dyn + (size_t)(r0 + 16*rt + 4*quad + r) * 32 + 16*ct + l16,
                  acc[rt][ct][r]);
}

// ---------------------------------------------------------------------------
// k1_qv v2: 64-node tile, operand-swapped MFMA (computes C^T so each lane owns
// 4 consecutive output channels -> packed b64 LDS writes everywhere).
// D[o][n] = W[o][c] * XT[n][c]^T ; A=W frags, B=XT frags (identical reg
// contents to v1, swapped call order). grid 64*32 = 2048 x 256.
// ---------------------------------------------------------------------------
__global__ __launch_bounds__(256) void k1_qv(const float* __restrict__ x,
    const ushort_t* __restrict__ wqb, const ushort_t* __restrict__ wvb,
    const float* __restrict__ qbias, const float* __restrict__ vbias,
    ushort_t* __restrict__ QsT, ushort_t* __restrict__ VT)
{
  int bid = blockIdx.x; int b = bid >> 5; int n0 = (bid & 31) * 64;
  int tid = threadIdx.x; int wv = tid >> 6; int lane = tid & 63;
  int quad = lane >> 4; int l16 = lane & 15;
  __shared__ __align__(16) ushort_t XT[64][136];   // x^T bf16, later V out
  __shared__ __align__(16) ushort_t QO[64][136];   // Q out

  // A-frags of W: lane l16 = output-channel row o, 8 consecutive c per quad
  uint4 wq[2][4], wvv[2][4];
  #pragma unroll
  for (int ct = 0; ct < 2; ++ct)
    #pragma unroll
    for (int k0 = 0; k0 < 4; ++k0) {
      int off = (32 * wv + 16 * ct + l16) * 128 + 32 * k0 + 8 * quad;
      wq[ct][k0]  = *(const uint4*)(wqb + off);
      wvv[ct][k0] = *(const uint4*)(wvb + off);
    }
  // biases for the 4 consecutive channels this lane owns (C^T rows)
  float4 qb4[2], vb4[2];
  #pragma unroll
  for (int ct = 0; ct < 2; ++ct) {
    qb4[ct] = *(const float4*)(qbias + 32 * wv + 16 * ct + 4 * quad);
    vb4[ct] = *(const float4*)(vbias + 32 * wv + 16 * ct + 4 * quad);
  }

  // stage x [128c][64n] fp32 -> XT[n][c] bf16; 4c x 4n micro-tile per thread,
  // packed b64 writes (4 channels per write)
  #pragma unroll
  for (int p = 0; p < 2; ++p) {
    int c4 = 4 * ((tid >> 4) + 16 * p);
    int n4 = 4 * (tid & 15);
    float4 r[4];
    #pragma unroll
    for (int j = 0; j < 4; ++j)
      r[j] = *(const float4*)(x + (size_t)(b * 128 + c4 + j) * 2048 + n0 + n4);
    #pragma unroll
    for (int i = 0; i < 4; ++i) {
      U16x4 w;
      w.s[0] = f2b(((const float*)&r[0])[i]);
      w.s[1] = f2b(((const float*)&r[1])[i]);
      w.s[2] = f2b(((const float*)&r[2])[i]);
      w.s[3] = f2b(((const float*)&r[3])[i]);
      *(uint2*)&XT[n4 + i][c4] = w.u;
    }
  }
  __syncthreads();

  f32x4 zero4 = {0.f,0.f,0.f,0.f};
  f32x4 av[4][2];   // V accumulators persist across nt

  #pragma unroll
  for (int nt = 0; nt < 4; ++nt) {
    f32x4 aq[2]; aq[0] = zero4; aq[1] = zero4;
    f32x4 avv[2]; avv[0] = zero4; avv[1] = zero4;
    #pragma unroll
    for (int k0 = 0; k0 < 4; ++k0) {
      bf16x8 bfrag = *(const bf16x8*)&XT[16 * nt + l16][32 * k0 + 8 * quad];
      #pragma unroll
      for (int ct = 0; ct < 2; ++ct) {
        aq[ct]  = __builtin_amdgcn_mfma_f32_16x16x32_bf16(as_bf16x8(wq[ct][k0]),  bfrag, aq[ct],  0, 0, 0);
        avv[ct] = __builtin_amdgcn_mfma_f32_16x16x32_bf16(as_bf16x8(wvv[ct][k0]), bfrag, avv[ct], 0, 0, 0);
      }
    }
    // Q softmax over this head's 32 channels for node n = n0+16nt+l16.
    // Channels live in {ct(2) x r(4)} in-register and quad(4) across lanes.
    float sq[2][4]; float mx = -1e30f;
    #pragma unroll
    for (int ct = 0; ct < 2; ++ct)
      #pragma unroll
      for (int r = 0; r < 4; ++r) {
        sq[ct][r] = fmaxf(aq[ct][r] + ((const float*)&qb4[ct])[r], 0.f) * INVS;
        mx = fmaxf(mx, sq[ct][r]);
      }
    mx = fmaxf(mx, __shfl_xor(mx, 16));
    mx = fmaxf(mx, __shfl_xor(mx, 32));
    float sum = 0.f;
    #pragma unroll
    for (int ct = 0; ct < 2; ++ct)
      #pragma unroll
      for (int r = 0; r < 4; ++r) { sq[ct][r] = __expf(sq[ct][r] - mx); sum += sq[ct][r]; }
    sum += __shfl_xor(sum, 16);
    sum += __shfl_xor(sum, 32);
    float inv = 1.f / sum;
    #pragma unroll
    for (int ct = 0; ct < 2; ++ct) {
      U16x4 w;
      #pragma unroll
      for (int r = 0; r < 4; ++r) w.s[r] = f2b(sq[ct][r] * inv);
      *(uint2*)&QO[16 * nt + l16][32 * wv + 16 * ct + 4 * quad] = w.u;
    }
    av[nt][0] = avv[0]; av[nt][1] = avv[1];
  }
  __syncthreads();   // all XT reads done

  // V = relu(acc + bias) -> XT (reuse), packed b64
  #pragma unroll
  for (int nt = 0; nt < 4; ++nt)
    #pragma unroll
    for (int ct = 0; ct < 2; ++ct) {
      U16x4 w;
      #pragma unroll
      for (int r = 0; r < 4; ++r)
        w.s[r] = f2b(fmaxf(av[nt][ct][r] + ((const float*)&vb4[ct])[r], 0.f));
      *(uint2*)&XT[16 * nt + l16][32 * wv + 16 * ct + 4 * quad] = w.u;
    }
  __syncthreads();

  // coalesced bf16 stores [b][n][128]
  #pragma unroll
  for (int j = 0; j < 4; ++j) {
    int id = tid + 256 * j; int n = id >> 4; int u = id & 15;
    size_t go = (size_t)(b * 2048 + n0 + n) * 128 + 8 * u;
    *(uint4*)(QsT + go) = *(uint4*)&QO[n][8 * u];
    *(uint4*)(VT  + go) = *(uint4*)&XT[n][8 * u];
  }
}

// ---------------------------------------------------------------------------
// k2_kv: per-(b,h) GEMM kv[x][y] = sum_n keysT[h][x][n] * V[n][h*32+y] via
// MFMA. grid 512 = (b x 8 n-splits of 256) x 256; wave = head.
// Writes per-block partials (NO atomics) -> kvp[bid][h][y][x].
// ---------------------------------------------------------------------------
__global__ __launch_bounds__(256) void k2_kv(const ushort_t* __restrict__ keysT,
    const ushort_t* __restrict__ VT, float* __restrict__ kvp)
{
  int bid = blockIdx.x; int b = bid >> 3; int nb = (bid & 7) * 256;
  int tid = threadIdx.x; int wv = tid >> 6; int lane = tid & 63;
  int quad = lane >> 4; int l16 = lane & 15;
  __shared__ __align__(16) ushort_t Vraw[128][136];   // 34.8 KB

  f32x4 zero4 = {0.f,0.f,0.f,0.f};
  f32x4 acc[2][2];
  acc[0][0] = zero4; acc[0][1] = zero4; acc[1][0] = zero4; acc[1][1] = zero4;

  for (int chunk = 0; chunk < 2; ++chunk) {
    int nc = nb + 128 * chunk;
    if (chunk) __syncthreads();
    #pragma unroll
    for (int p = 0; p < 8; ++p) {
      int id = tid + 256 * p; int n = id >> 4; int g = id & 15;
      *(uint4*)&Vraw[n][8 * g] = *(const uint4*)(VT + (size_t)(b * 2048 + nc + n) * 128 + 8 * g);
    }
    __syncthreads();
    const ushort_t* kT = keysT + (size_t)(wv * 32) * 2048 + nc;
    #pragma unroll
    for (int ks = 0; ks < 4; ++ks) {
      int k0 = 32 * ks + 8 * quad;
      bf16x8 a0 = *(const bf16x8*)(kT + (size_t)l16 * 2048 + k0);
      bf16x8 a1 = *(const bf16x8*)(kT + (size_t)(16 + l16) * 2048 + k0);
      U16x8 b0, b1;
      #pragma unroll
      for (int j = 0; j < 8; ++j) {
        b0.s[j] = Vraw[k0 + j][32 * wv + l16];
        b1.s[j] = Vraw[k0 + j][32 * wv + 16 + l16];
      }
      acc[0][0] = __builtin_amdgcn_mfma_f32_16x16x32_bf16(a0, b0.b, acc[0][0], 0, 0, 0);
      acc[0][1] = __builtin_amdgcn_mfma_f32_16x16x32_bf16(a0, b1.b, acc[0][1], 0, 0, 0);
      acc[1][0] = __builtin_amdgcn_mfma_f32_16x16x32_bf16(a1, b0.b, acc[1][0], 0, 0, 0);
      acc[1][1] = __builtin_amdgcn_mfma_f32_16x16x32_bf16(a1, b1.b, acc[1][1], 0, 0, 0);
    }
  }

  float* dst = kvp + (size_t)bid * 4096 + wv * 1024;   // [bid][h][y][x]
  #pragma unroll
  for (int yt = 0; yt < 2; ++yt)
    #pragma unroll
    for (int xt = 0; xt < 2; ++xt)
      #pragma unroll
      for (int r = 0; r < 4; ++r)
        dst[(16 * yt + l16) * 32 + 16 * xt + 4 * quad + r] = acc[xt][yt][r];
}

// ---------------------------------------------------------------------------
// kred: kvws[b][i] = sum over 8 n-split partials. grid 1024 x 256, coalesced.
// ---------------------------------------------------------------------------
__global__ __launch_bounds__(256) void kred(const float* __restrict__ kvp,
    float* __restrict__ kvws)
{
  int gid = blockIdx.x * 256 + threadIdx.x;   // 262144 outputs
  int b = gid >> 12; int i = gid & 4095;
  const float* p = kvp + (size_t)(b * 8) * 4096 + i;
  float s = 0.f;
  #pragma unroll
  for (int t = 0; t < 8; ++t) s += p[t * 4096];
  kvws[gid] = s;
}

// ---------------------------------------------------------------------------
// k3_out: attn_qkv (block-diag GEMM, K=32/head) + Ws*V + bias_dyn -> MID(LDS),
// then final conv GEMM + relu + affine residual. Block: 64 nodes of one b.
// grid 64*32 = 2048 x 256; wave w owns head w / c_out group w.
// ---------------------------------------------------------------------------
__global__ __launch_bounds__(256) void k3_out(const ushort_t* __restrict__ QsT,
    const ushort_t* __restrict__ VT, const float* __restrict__ kvws,
    const float* __restrict__ bias_dyn, const ushort_t* __restrict__ wcb,
    const float* __restrict__ cbias, const float* __restrict__ wpool,
    const float* __restrict__ aff_w, const float* __restrict__ aff_b,
    float* __restrict__ out)
{
  int bid = blockIdx.x; int b = bid >> 5; int n0 = (bid & 31) * 64;
  int tid = threadIdx.x; int wv = tid >> 6; int lane = tid & 63;
  int quad = lane >> 4; int l16 = lane & 15;
  __shared__ __align__(16) ushort_t kvT[4][32][40];   // [h][y][x] bf16, padded
  __shared__ __align__(16) ushort_t MID[64][136];
  __shared__ __align__(16) ushort_t VL[64][132];      // V tile, bf16
  __shared__ __align__(16) float    BD[64][36];       // bias_dyn tile

  float Ws = 0.f;
  #pragma unroll
  for (int i = 0; i < 9; ++i) Ws += wpool[i];

  uint4 wc[2][4];
  #pragma unroll
  for (int mt = 0; mt < 2; ++mt)
    #pragma unroll
    for (int k0 = 0; k0 < 4; ++k0)
      wc[mt][k0] = *(const uint4*)(wcb + (32 * wv + 16 * mt + l16) * 128 + 32 * k0 + 8 * quad);

  #pragma unroll
  for (int p = 0; p < 16; ++p) {
    int id = tid + 256 * p;
    kvT[id >> 10][(id >> 5) & 31][id & 31] = f2b(kvws[(size_t)b * 4096 + id]);
  }
  #pragma unroll
  for (int p = 0; p < 4; ++p) {        // V tile: 64 rows x 128 cols bf16
    int id = tid + 256 * p; int n = id >> 4; int u = id & 15;
    *(uint4*)&VL[n][8 * u] = *(const uint4*)(VT + (size_t)(b * 2048 + n0 + n) * 128 + 8 * u);
  }
  #pragma unroll
  for (int p = 0; p < 2; ++p) {        // bias_dyn tile: 64 rows x 32
    int id = tid + 256 * p; int n = id >> 3; int g = id & 7;
    *(float4*)&BD[n][4 * g] = *(const float4*)(bias_dyn + (size_t)(n0 + n) * 32 + 4 * g);
  }
  __syncthreads();

  f32x4 zero4 = {0.f,0.f,0.f,0.f};
  f32x4 acc1[4][2];
  #pragma unroll
  for (int nt = 0; nt < 4; ++nt) { acc1[nt][0] = zero4; acc1[nt][1] = zero4; }
  #pragma unroll
  for (int nt = 0; nt < 4; ++nt) {
    bf16x8 aq = *(const bf16x8*)(QsT + (size_t)(b * 2048 + n0 + 16 * nt + l16) * 128 + 32 * wv + 8 * quad);
    #pragma unroll
    for (int ct = 0; ct < 2; ++ct)
      acc1[nt][ct] = __builtin_amdgcn_mfma_f32_16x16x32_bf16(
          aq, *(const bf16x8*)&kvT[wv][16 * ct + l16][8 * quad], acc1[nt][ct], 0, 0, 0);
  }

  // epilogue 1: MID = attn_qkv + Ws*V + bias_dyn (bf16 in LDS)
  #pragma unroll
  for (int nt = 0; nt < 4; ++nt)
    #pragma unroll
    for (int ct = 0; ct < 2; ++ct)
      #pragma unroll
      for (int r = 0; r < 4; ++r) {
        int nl = 16 * nt + 4 * quad + r;
        int cc = 32 * wv + 16 * ct + l16;
        float v = b2f(VL[nl][cc]);
        float bd = BD[nl][16 * ct + l16];
        MID[nl][cc] = f2b(acc1[nt][ct][r] + Ws * v + bd);
      }
  __syncthreads();

  f32x4 acc2[2][4];
  #pragma unroll
  for (int mt = 0; mt < 2; ++mt)
    #pragma unroll
    for (int nt = 0; nt < 4; ++nt) acc2[mt][nt] = zero4;
  #pragma unroll
  for (int k0 = 0; k0 < 4; ++k0) {
    bf16x8 bb[4];
    #pragma unroll
    for (int nt = 0; nt < 4; ++nt)
      bb[nt] = *(const bf16x8*)&MID[16 * nt + l16][32 * k0 + 8 * quad];
    #pragma unroll
    for (int mt = 0; mt < 2; ++mt)
      #pragma unroll
      for (int nt = 0; nt < 4; ++nt)
        acc2[mt][nt] = __builtin_amdgcn_mfma_f32_16x16x32_bf16(
            as_bf16x8(wc[mt][k0]), bb[nt], acc2[mt][nt], 0, 0, 0);
  }

  // epilogue 2: relu(+cb), affine residual, store fp32
  #pragma unroll
  for (int mt = 0; mt < 2; ++mt)
    #pragma unroll
    for (int nt = 0; nt < 4; ++nt)
      #pragma unroll
      for (int r = 0; r < 4; ++r) {
        int c_out = 32 * wv + 16 * mt + 4 * quad + r;
        int nn2 = n0 + 16 * nt + l16;
        float yv = fmaxf(acc2[mt][nt][r] + cbias[c_out], 0.f);
        size_t ai = (size_t)c_out * 2048 + nn2;
        float awv = aff_w[ai], abv = aff_b[ai];
        out[(size_t)(b * 128 + c_out) * 2048 + nn2] = yv * awv + abv + yv;
      }
}

// ---------------------------------------------------------------------------
extern "C" void kernel_launch(void* const* d_in, const int* in_sizes, int n_in,
                              void* d_out, int out_size, void* d_ws, size_t ws_size,
                              hipStream_t stream)
{
  const float* x      = (const float*)d_in[0];
  const float* qw     = (const float*)d_in[1];
  const float* qb     = (const float*)d_in[2];
  const float* vw     = (const float*)d_in[3];
  const float* vb     = (const float*)d_in[4];
  const float* cw     = (const float*)d_in[5];
  const float* cb     = (const float*)d_in[6];
  const float* memory = (const float*)d_in[7];
  const float* nv1    = (const float*)d_in[8];
  const float* nv2    = (const float*)d_in[9];
  const float* wpool  = (const float*)d_in[10];
  const float* bpool  = (const float*)d_in[11];
  const float* aw     = (const float*)d_in[12];
  const float* ab     = (const float*)d_in[13];
  float* out = (float*)d_out;

  char* ws = (char*)d_ws;
  ushort_t* QsT      = (ushort_t*)(ws);                 // 33,554,432 B
  ushort_t* VT       = (ushort_t*)(ws + 33554432);      // 33,554,432 B
  float*    kvws     = (float*)   (ws + 67108864);      //  1,048,576 B
  ushort_t* keysT    = (ushort_t*)(ws + 68157440);      //    524,288 B
  float*    bias_dyn = (float*)   (ws + 69206016);      //    262,144 B
  ushort_t* wqb      = (ushort_t*)(ws + 69468160);      //     32,768 B
  ushort_t* wvb      = (ushort_t*)(ws + 69500928);      //     32,768 B
  ushort_t* wcb      = (ushort_t*)(ws + 69533696);      //     32,768 B
  ushort_t* Ebuf     = (ushort_t*)(ws + 69566464);      //  8,388,608 B
  ushort_t* bpT      = (ushort_t*)(ws + 77955072);      //    131,072 B (end 78,086,144)
  float*    kvp      = (float*)Ebuf;                    //  8,388,608 B (Ebuf dead after kb2)

  k0_prep<<<256, 256, 0, stream>>>(qw, vw, cw, memory, bpool, wqb, wvb, wcb,
                                   keysT, bias_dyn, bpT);
  kb1<<<2048, 256, 0, stream>>>(nv1, nv2, Ebuf);
  kb2<<<128, 256, 0, stream>>>(Ebuf, bpT, bias_dyn);
  k1_qv<<<2048, 256, 0, stream>>>(x, wqb, wvb, qb, vb, QsT, VT);
  k2_kv<<<512, 256, 0, stream>>>(keysT, VT, kvp);
  kred<<<1024, 256, 0, stream>>>(kvp, kvws);
  k3_out<<<2048, 256, 0, stream>>>(QsT, VT, kvws, bias_dyn, wcb, cb, wpool, aw, ab, out);
}